// Round 21
// baseline (526.372 us; speedup 1.0000x reference)
//
#include <hip/hip_runtime.h>
#include <hip/hip_bf16.h>

#define NN 100000      // nodes
#define NE 200000      // edges
#define NF 56          // atom feats
#define HD 256         // hidden
#define NG 2048        // graphs

#define SCAN_CH 512
#define NCH ((NN + SCAN_CH - 1) / SCAN_CH)   // 196 chunks
#define EB ((NE + 255) / 256)                // csr_fill edge blocks

#define AGB 6250       // aggregate blocks (16 nodes each, NN/16 exact)

typedef __bf16 bf16x8 __attribute__((ext_vector_type(8)));
typedef __bf16 bf16x4 __attribute__((ext_vector_type(4)));
typedef float  floatx4 __attribute__((ext_vector_type(4)));

// ---- param prep (merged): f<NF delta-row GEMM; f==NF base row; f==NF+1 w2lw -
__global__ void prep_params(const float* __restrict__ emb, const float* __restrict__ Ws,
                            const float* __restrict__ bs, const float* __restrict__ lw,
                            float* __restrict__ dW0, float* __restrict__ bW0,
                            float* __restrict__ w2lw, float* __restrict__ b2lw) {
    __shared__ float row[HD];
    int c = threadIdx.x;
    int f = blockIdx.x;
    if (f == NF + 1) {   // layer-2 collapse params
        const float* W2 = Ws + (size_t)2 * HD * HD;
        float acc = 0.f;
        for (int k = 0; k < HD; ++k) acc += W2[(size_t)c * HD + k] * lw[k];
        w2lw[c] = acc;
        row[c] = bs[2 * HD + c] * lw[c];
        __syncthreads();
        for (int off = 128; off > 0; off >>= 1) {
            if (c < off) row[c] += row[c + off];
            __syncthreads();
        }
        if (c == 0) *b2lw = row[0];
        return;
    }
    if (f < NF) {
        row[c] = emb[(f * 2 + 1) * HD + c] - emb[(f * 2 + 0) * HD + c];
    } else {
        float s = 0.f;
        for (int ff = 0; ff < NF; ++ff) s += emb[(ff * 2) * HD + c];
        row[c] = s;
    }
    __syncthreads();
    float acc = 0.f;
    for (int k = 0; k < HD; ++k) acc += row[k] * Ws[k * HD + c];   // W0
    if (f < NF) dW0[f * HD + c] = acc; else bW0[c] = acc;
}

// merged weight converts: l==0 -> Wt (layer-1 weights, Ws[1]); l==1 -> dW0t
__global__ void cvt_w_all(const float* __restrict__ Ws, const float* __restrict__ dW0,
                          __bf16* __restrict__ Wt, __bf16* __restrict__ dW0t) {
    int n = blockIdx.x, l = blockIdx.y, k = threadIdx.x;
    if (l == 0) {
        Wt[(size_t)n * HD + k] = (__bf16)Ws[(size_t)1 * HD * HD + (size_t)k * HD + n];
    } else if (k < 64) {
        dW0t[n * 64 + k] = (k < NF) ? (__bf16)dW0[k * HD + n] : (__bf16)0.f;
    }
}

// ---- degree ------------------------------------------------------------------
__global__ void deg_kernel(const int* __restrict__ dst, unsigned* __restrict__ deg, int E) {
    int e = blockIdx.x * blockDim.x + threadIdx.x;
    if (e < E) atomicAdd(&deg[dst[e]], 1u);
}

// merged: per-chunk degree sum (for scan) + dinv/selfn
__global__ void chunk_sum_dinv(const unsigned* __restrict__ deg, unsigned* __restrict__ csum,
                               float* __restrict__ dinv, float* __restrict__ selfn) {
    __shared__ unsigned s[SCAN_CH];
    int t = threadIdx.x;
    int base = blockIdx.x * SCAN_CH;
    unsigned v = (base + t < NN) ? deg[base + t] : 0u;
    s[t] = v;
    if (base + t < NN) {
        float d = (float)(v + 1u);   // +1 self loop
        dinv[base + t]  = rsqrtf(d);
        selfn[base + t] = 1.0f / d;
    }
    __syncthreads();
    for (int off = SCAN_CH / 2; off > 0; off >>= 1) {
        if (t < off) s[t] += s[t + off];
        __syncthreads();
    }
    if (t == 0) csum[blockIdx.x] = s[0];
}

// chunk_apply with INLINE scan of csum (each block re-scans 196 chunk sums)
__global__ void chunk_apply(const unsigned* __restrict__ deg, const unsigned* __restrict__ csum,
                            unsigned* __restrict__ row_start, unsigned* __restrict__ cursor) {
    __shared__ unsigned s[SCAN_CH];
    __shared__ unsigned cs[256];
    int t = threadIdx.x;
    if (t < 256) cs[t] = (t < NCH) ? csum[t] : 0u;
    __syncthreads();
    for (int off = 1; off < 256; off <<= 1) {
        unsigned add = (t < 256 && t >= off) ? cs[t - off] : 0u;
        __syncthreads();
        if (t < 256) cs[t] += add;
        __syncthreads();
    }
    unsigned chunk_base = (blockIdx.x == 0) ? 0u : cs[blockIdx.x - 1];

    int base = blockIdx.x * SCAN_CH;
    unsigned v = (base + t < NN) ? deg[base + t] : 0u;
    s[t] = v;
    __syncthreads();
    for (int off = 1; off < SCAN_CH; off <<= 1) {
        unsigned add = (t >= off) ? s[t - off] : 0u;
        __syncthreads();
        s[t] += add;
        __syncthreads();
    }
    if (base + t < NN) {
        unsigned rs = chunk_base + s[t] - v;   // exclusive scan value
        row_start[base + t] = rs;
        cursor[base + t] = rs;
    }
    if (blockIdx.x == 0 && t == 0) row_start[NN] = NE;
}

// csr_fill (inline norm) + graph_bounds merged into the tail blocks
__global__ void csr_fill_gb(const int* __restrict__ src, const int* __restrict__ dst,
                            const float* __restrict__ dinv, unsigned* __restrict__ cursor,
                            int* __restrict__ ecol, float* __restrict__ enorm,
                            const int* __restrict__ batch, unsigned* __restrict__ gstart) {
    int t = threadIdx.x;
    if (blockIdx.x < EB) {
        int e = blockIdx.x * 256 + t;
        if (e < NE) {
            int s = src[e], d = dst[e];
            unsigned pos = atomicAdd(&cursor[d], 1u);
            ecol[pos] = s;
            enorm[pos] = dinv[s] * dinv[d];
        }
    } else {
        int g = (blockIdx.x - EB) * 256 + t;
        if (g <= NG) {
            int lo = 0, hi = NN;
            while (lo < hi) {
                int mid = (lo + hi) >> 1;
                if (batch[mid] < g) lo = mid + 1; else hi = mid;
            }
            gstart[g] = (unsigned)lo;
        }
    }
}

// ---- MFMA encoder: hw0 = X @ dW0t^T + bW0, X binary [NN,56] pad K->64 -------
#define ELSTR 68
__global__ void __launch_bounds__(256) encoder_mfma(const int* __restrict__ x,
                                                    const __bf16* __restrict__ dW0t,
                                                    const float* __restrict__ bW0,
                                                    __bf16* __restrict__ C) {
    __shared__ __bf16 sA[128 * ELSTR];   // 17408 B
    __shared__ __bf16 sB[128 * ELSTR];   // 17408 B
    int t = threadIdx.x;
    int m0 = blockIdx.x * 128;
    int n0 = blockIdx.y * 128;
    int lane = t & 63, w = t >> 6;
    int quad = lane >> 4, l16 = lane & 15;
    int mw = (w & 1) * 64, nw = (w >> 1) * 64;

    {
        int r = t >> 1;
        int kh = (t & 1) * 32;
        int row = m0 + r;
        int nreal = (kh == 0) ? 32 : 24;
        #pragma unroll
        for (int j = 0; j < 8; ++j) {
            bf16x4 b;
            if (row < NN && j * 4 < nreal) {
                int4 iv = *(const int4*)&x[(size_t)row * NF + kh + j * 4];
                b[0] = (__bf16)(float)iv.x;
                b[1] = (__bf16)(float)iv.y;
                b[2] = (__bf16)(float)iv.z;
                b[3] = (__bf16)(float)iv.w;
            } else {
                b[0] = b[1] = b[2] = b[3] = (__bf16)0.f;
            }
            *(bf16x4*)&sA[r * ELSTR + kh + j * 4] = b;
        }
    }
    {
        int bn = t >> 1;
        int kh = (t & 1) * 32;
        #pragma unroll
        for (int j = 0; j < 4; ++j) {
            bf16x8 v = *(const bf16x8*)&dW0t[(size_t)(n0 + bn) * 64 + kh + j * 8];
            *(bf16x8*)&sB[bn * ELSTR + kh + j * 8] = v;
        }
    }
    __syncthreads();

    floatx4 acc[4][4] = {};
    #pragma unroll
    for (int s = 0; s < 2; ++s) {
        bf16x8 af[4], bfr[4];
        #pragma unroll
        for (int i = 0; i < 4; ++i)
            af[i] = *(const bf16x8*)&sA[(mw + i * 16 + l16) * ELSTR + s * 32 + quad * 8];
        #pragma unroll
        for (int i = 0; i < 4; ++i)
            bfr[i] = *(const bf16x8*)&sB[(nw + i * 16 + l16) * ELSTR + s * 32 + quad * 8];
        #pragma unroll
        for (int mi = 0; mi < 4; ++mi)
            #pragma unroll
            for (int ni = 0; ni < 4; ++ni)
                acc[mi][ni] = __builtin_amdgcn_mfma_f32_16x16x32_bf16(
                    af[mi], bfr[ni], acc[mi][ni], 0, 0, 0);
    }

    float bw[4];
    #pragma unroll
    for (int ni = 0; ni < 4; ++ni) bw[ni] = bW0[n0 + nw + ni * 16 + l16];
    #pragma unroll
    for (int mi = 0; mi < 4; ++mi) {
        #pragma unroll
        for (int r = 0; r < 4; ++r) {
            int row = m0 + mw + mi * 16 + quad * 4 + r;
            if (row < NN) {
                #pragma unroll
                for (int ni = 0; ni < 4; ++ni)
                    C[(size_t)row * HD + n0 + nw + ni * 16 + l16] =
                        (__bf16)(acc[mi][ni][r] + bw[ni]);
            }
        }
    }
}

// ---- bf16 MFMA GEMM: 128x256 tile (full N), 512 thr / 8 waves (2m x 4n) -----
#define LSTR 36
__global__ void __launch_bounds__(512) gemm_mfma(const __bf16* __restrict__ A,
                                                 const __bf16* __restrict__ Wt,
                                                 __bf16* __restrict__ C, int M,
                                                 const float* __restrict__ ascale,
                                                 const float* __restrict__ ashift) {
    __shared__ __bf16 sA[128 * LSTR];   //  9216 B
    __shared__ __bf16 sB[256 * LSTR];   // 18432 B
    int t = threadIdx.x;                // 0..511
    int m0 = blockIdx.x * 128;
    int lane = t & 63, w = t >> 6;      // 8 waves
    int quad = lane >> 4, l16 = lane & 15;
    int mw = (w & 1) * 64;
    int nw = (w >> 1) * 64;             // 0,64,128,192

    int ar = t >> 2;          // A-stage row 0..127
    int ak = (t & 3) * 8;     // 16-B k-offset within 32-tile
    int bn = t >> 1;          // B-stage LDS row (n), 0..255
    int bk = (t & 1) * 16;    // k-offset (two bf16x8)

    auto ldA = [&](int k0, bf16x8& pa) {
        float4 s0 = *(const float4*)&ascale[k0 + ak];
        float4 s1 = *(const float4*)&ascale[k0 + ak + 4];
        float4 h0 = *(const float4*)&ashift[k0 + ak];
        float4 h1 = *(const float4*)&ashift[k0 + ak + 4];
        int row = m0 + ar;
        bf16x8 a = {};
        if (row < M) a = *(const bf16x8*)&A[(size_t)row * HD + k0 + ak];
        bf16x8 b;
        b[0] = (__bf16)fmaxf((float)a[0] * s0.x + h0.x, 0.f);
        b[1] = (__bf16)fmaxf((float)a[1] * s0.y + h0.y, 0.f);
        b[2] = (__bf16)fmaxf((float)a[2] * s0.z + h0.z, 0.f);
        b[3] = (__bf16)fmaxf((float)a[3] * s0.w + h0.w, 0.f);
        b[4] = (__bf16)fmaxf((float)a[4] * s1.x + h1.x, 0.f);
        b[5] = (__bf16)fmaxf((float)a[5] * s1.y + h1.y, 0.f);
        b[6] = (__bf16)fmaxf((float)a[6] * s1.z + h1.z, 0.f);
        b[7] = (__bf16)fmaxf((float)a[7] * s1.w + h1.w, 0.f);
        pa = b;
    };
    auto ldB = [&](int k0, bf16x8 pb[2]) {
        #pragma unroll
        for (int j = 0; j < 2; ++j)
            pb[j] = *(const bf16x8*)&Wt[(size_t)bn * HD + k0 + bk + j * 8];
    };

    bf16x8 pa, pb[2];
    ldA(0, pa);
    ldB(0, pb);

    floatx4 acc[4][4] = {};

    for (int k0 = 0; k0 < 256; k0 += 32) {
        *(bf16x8*)&sA[ar * LSTR + ak] = pa;
        *(bf16x8*)&sB[bn * LSTR + bk]     = pb[0];
        *(bf16x8*)&sB[bn * LSTR + bk + 8] = pb[1];
        __syncthreads();

        if (k0 + 32 < 256) {
            ldA(k0 + 32, pa);
            ldB(k0 + 32, pb);
        }

        bf16x8 af[4], bfr[4];
        #pragma unroll
        for (int i = 0; i < 4; ++i)
            af[i] = *(const bf16x8*)&sA[(mw + i * 16 + l16) * LSTR + quad * 8];
        #pragma unroll
        for (int i = 0; i < 4; ++i)
            bfr[i] = *(const bf16x8*)&sB[(nw + i * 16 + l16) * LSTR + quad * 8];
        #pragma unroll
        for (int mi = 0; mi < 4; ++mi)
            #pragma unroll
            for (int ni = 0; ni < 4; ++ni)
                acc[mi][ni] = __builtin_amdgcn_mfma_f32_16x16x32_bf16(
                    af[mi], bfr[ni], acc[mi][ni], 0, 0, 0);
        __syncthreads();
    }

    #pragma unroll
    for (int mi = 0; mi < 4; ++mi) {
        #pragma unroll
        for (int r = 0; r < 4; ++r) {
            int row = m0 + mw + mi * 16 + quad * 4 + r;
            if (row < M) {
                #pragma unroll
                for (int ni = 0; ni < 4; ++ni)
                    C[(size_t)row * HD + nw + ni * 16 + l16] = (__bf16)acc[mi][ni][r];
            }
        }
    }
}

// ---- CSR gather-aggregate + fused BN partials (1024 thr = 16 waves/nodes) ---
// part==nullptr -> skip stats. Partials CONTIGUOUS per block: part[block*512+c]
// (sum), part[block*512+256+c] (sumsq) -> 2 KB dense write, 12.8 MB total.
__global__ void __launch_bounds__(1024) gcn_aggregate(const __bf16* __restrict__ hw,
                                                      const float* __restrict__ selfn,
                                                      const float* __restrict__ bias,
                                                      const unsigned* __restrict__ row_start,
                                                      const int* __restrict__ ecol,
                                                      const float* __restrict__ enorm,
                                                      __bf16* __restrict__ agg,
                                                      float* __restrict__ part) {
    __shared__ float4 ssum[16][64];   // 16 KB
    __shared__ float4 sss[16][64];    // 16 KB
    int t = threadIdx.x;
    int l = t & 63, w = t >> 6;       // 16 waves
    int n = blockIdx.x * 16 + w;      // grid == NN/16 exactly
    int c4 = l * 4;
    float s = selfn[n];
    bf16x4 hv = *(const bf16x4*)&hw[(size_t)n * HD + c4];
    float4 acc;
    acc.x = (float)hv[0] * s + bias[c4 + 0];
    acc.y = (float)hv[1] * s + bias[c4 + 1];
    acc.z = (float)hv[2] * s + bias[c4 + 2];
    acc.w = (float)hv[3] * s + bias[c4 + 3];
    unsigned e0 = row_start[n], e1 = row_start[n + 1];
    unsigned e = e0;
    for (; e + 4 <= e1; e += 4) {
        int sv0 = ecol[e], sv1 = ecol[e + 1], sv2 = ecol[e + 2], sv3 = ecol[e + 3];
        float nm0 = enorm[e], nm1 = enorm[e + 1], nm2 = enorm[e + 2], nm3 = enorm[e + 3];
        bf16x4 u0 = *(const bf16x4*)&hw[(size_t)sv0 * HD + c4];
        bf16x4 u1 = *(const bf16x4*)&hw[(size_t)sv1 * HD + c4];
        bf16x4 u2 = *(const bf16x4*)&hw[(size_t)sv2 * HD + c4];
        bf16x4 u3 = *(const bf16x4*)&hw[(size_t)sv3 * HD + c4];
        acc.x += (float)u0[0] * nm0 + (float)u1[0] * nm1 + (float)u2[0] * nm2 + (float)u3[0] * nm3;
        acc.y += (float)u0[1] * nm0 + (float)u1[1] * nm1 + (float)u2[1] * nm2 + (float)u3[1] * nm3;
        acc.z += (float)u0[2] * nm0 + (float)u1[2] * nm1 + (float)u2[2] * nm2 + (float)u3[2] * nm3;
        acc.w += (float)u0[3] * nm0 + (float)u1[3] * nm1 + (float)u2[3] * nm2 + (float)u3[3] * nm3;
    }
    for (; e + 2 <= e1; e += 2) {
        int sv0 = ecol[e], sv1 = ecol[e + 1];
        float nm0 = enorm[e], nm1 = enorm[e + 1];
        bf16x4 u0 = *(const bf16x4*)&hw[(size_t)sv0 * HD + c4];
        bf16x4 u1 = *(const bf16x4*)&hw[(size_t)sv1 * HD + c4];
        acc.x += (float)u0[0] * nm0 + (float)u1[0] * nm1;
        acc.y += (float)u0[1] * nm0 + (float)u1[1] * nm1;
        acc.z += (float)u0[2] * nm0 + (float)u1[2] * nm1;
        acc.w += (float)u0[3] * nm0 + (float)u1[3] * nm1;
    }
    if (e < e1) {
        int sv = ecol[e];
        float nm = enorm[e];
        bf16x4 u = *(const bf16x4*)&hw[(size_t)sv * HD + c4];
        acc.x += (float)u[0] * nm;
        acc.y += (float)u[1] * nm;
        acc.z += (float)u[2] * nm;
        acc.w += (float)u[3] * nm;
    }
    bf16x4 o;
    o[0] = (__bf16)acc.x; o[1] = (__bf16)acc.y;
    o[2] = (__bf16)acc.z; o[3] = (__bf16)acc.w;
    *(bf16x4*)&agg[(size_t)n * HD + c4] = o;

    if (part) {
        ssum[w][l] = acc;
        sss[w][l]  = make_float4(acc.x * acc.x, acc.y * acc.y, acc.z * acc.z, acc.w * acc.w);
        __syncthreads();
        if (w == 0) {
            float4 a = ssum[0][l], q = sss[0][l];
            #pragma unroll
            for (int i = 1; i < 16; ++i) {
                float4 b = ssum[i][l], r = sss[i][l];
                a.x += b.x; a.y += b.y; a.z += b.z; a.w += b.w;
                q.x += r.x; q.y += r.y; q.z += r.z; q.w += r.w;
            }
            *(float4*)&part[(size_t)blockIdx.x * 512 + c4]       = a;
            *(float4*)&part[(size_t)blockIdx.x * 512 + 256 + c4] = q;
        }
    }
}

// ---- bn_scale: 16 blocks x 16 columns; dense line reads of part[block][512] -
__global__ void __launch_bounds__(256) bn_scale(const float* __restrict__ part,
                                                const float* __restrict__ gamma,
                                                const float* __restrict__ beta,
                                                float* __restrict__ scale,
                                                float* __restrict__ shift) {
    __shared__ float rs[16][16], rq[16][16];
    int t = threadIdx.x;
    int cc = t & 15, jj = t >> 4;
    int c = blockIdx.x * 16 + cc;
    float s = 0.f, q = 0.f;
    for (int j = jj; j < AGB; j += 16) {
        s += part[(size_t)j * 512 + c];
        q += part[(size_t)j * 512 + 256 + c];
    }
    rs[jj][cc] = s; rq[jj][cc] = q;
    __syncthreads();
    if (jj == 0) {
        #pragma unroll
        for (int i = 1; i < 16; ++i) { s += rs[i][cc]; q += rq[i][cc]; }
        const float inv_n = 1.0f / (float)NN;
        float mu  = s * inv_n;
        float var = q * inv_n - mu * mu;
        float rstd = rsqrtf(var + 1e-5f);
        float sc = gamma[c] * rstd;
        scale[c] = sc;
        shift[c] = beta[c] - mu * sc;
    }
}

// ---- layer-2 collapse: z[n] = relu_bn(buf0[n]) . w2lw  (one wave per node) --
__global__ void __launch_bounds__(256) bn_dot(const __bf16* __restrict__ h,
                                              const float* __restrict__ scale,
                                              const float* __restrict__ shift,
                                              const float* __restrict__ w2lw,
                                              float* __restrict__ z) {
    int tid = blockIdx.x * 256 + threadIdx.x;
    int n = tid >> 6;
    if (n >= NN) return;
    int l = tid & 63;
    int c4 = l * 4;
    bf16x4 a = *(const bf16x4*)&h[(size_t)n * HD + c4];
    float4 sc = *(const float4*)&scale[c4];
    float4 sh = *(const float4*)&shift[c4];
    float4 wv = *(const float4*)&w2lw[c4];
    float d = fmaxf((float)a[0] * sc.x + sh.x, 0.f) * wv.x
            + fmaxf((float)a[1] * sc.y + sh.y, 0.f) * wv.y
            + fmaxf((float)a[2] * sc.z + sh.z, 0.f) * wv.z
            + fmaxf((float)a[3] * sc.w + sh.w, 0.f) * wv.w;
    #pragma unroll
    for (int off = 32; off > 0; off >>= 1) d += __shfl_down(d, off, 64);
    if (l == 0) z[n] = d;
}

// ---- fused final: per-graph wave; lanes stride nodes; scalar edge loop ------
__global__ void __launch_bounds__(256) pool_fused(const float* __restrict__ z,
                                                  const float* __restrict__ selfn,
                                                  const float* __restrict__ b2lw,
                                                  const unsigned* __restrict__ row_start,
                                                  const int* __restrict__ ecol,
                                                  const float* __restrict__ enorm,
                                                  const unsigned* __restrict__ gstart,
                                                  const float* __restrict__ lb,
                                                  float* __restrict__ out) {
    int tid = blockIdx.x * 256 + threadIdx.x;
    int g = tid >> 6;
    if (g >= NG) return;
    int l = tid & 63;
    unsigned s0 = gstart[g], s1 = gstart[g + 1];
    float bb = *b2lw;
    float s = 0.f;
    for (unsigned i = s0 + l; i < s1; i += 64) {
        float d = selfn[i] * z[i] + bb;
        unsigned e0 = row_start[i], e1 = row_start[i + 1];
        for (unsigned e = e0; e < e1; ++e)
            d += enorm[e] * z[ecol[e]];
        s += d;
    }
    #pragma unroll
    for (int off = 32; off > 0; off >>= 1) s += __shfl_down(s, off, 64);
    if (l == 0) out[g] = s / fmaxf((float)(s1 - s0), 1.0f) + lb[0];
}

// ---- driver -----------------------------------------------------------------
extern "C" void kernel_launch(void* const* d_in, const int* in_sizes, int n_in,
                              void* d_out, int out_size, void* d_ws, size_t ws_size,
                              hipStream_t stream) {
    const int*   x     = (const int*)d_in[0];
    const int*   ei    = (const int*)d_in[1];
    const int*   batch = (const int*)d_in[2];
    const float* emb   = (const float*)d_in[3];
    const float* Ws    = (const float*)d_in[4];
    const float* bs    = (const float*)d_in[5];
    const float* gam   = (const float*)d_in[6];
    const float* bet   = (const float*)d_in[7];
    const float* lw    = (const float*)d_in[8];
    const float* lb    = (const float*)d_in[9];
    float* out = (float*)d_out;

    const int* src = ei;
    const int* dst = ei + NE;

    // workspace carve-up (256-B aligned)
    char* p = (char*)d_ws;
    size_t off = 0;
    auto carve = [&](size_t bytes) { void* r = p + off; off = (off + bytes + 255) & ~(size_t)255; return r; };
    __bf16*   buf0   = (__bf16*)carve((size_t)NN * HD * 2);   // agg (bf16)
    __bf16*   buf1   = (__bf16*)carve((size_t)NN * HD * 2);   // hw  (bf16)
    float*    dW0    = (float*)carve(NF * HD * 4);
    float*    bW0    = (float*)carve(HD * 4);
    __bf16*   dW0t   = (__bf16*)carve(HD * 64 * 2);
    __bf16*   Wt     = (__bf16*)carve((size_t)HD * HD * 2);   // layer-1 only
    float*    w2lw   = (float*)carve(HD * 4);
    float*    b2lw   = (float*)carve(256);
    unsigned* deg    = (unsigned*)carve(NN * 4);
    float*    dinv   = (float*)carve(NN * 4);
    float*    selfn  = (float*)carve(NN * 4);
    unsigned* csum   = (unsigned*)carve(256 * 4);
    unsigned* row_s  = (unsigned*)carve((NN + 1) * 4);
    unsigned* cursor = (unsigned*)carve(NN * 4);
    int*      ecol   = (int*)carve(NE * 4);
    float*    enorm  = (float*)carve(NE * 4);
    float*    part   = (float*)carve((size_t)AGB * 512 * 4);   // 12.8 MB
    float*    scale  = (float*)carve(HD * 4);
    float*    shift  = (float*)carve(HD * 4);
    unsigned* gstart = (unsigned*)carve((NG + 1) * 4);
    float*    zbuf   = (float*)carve(NN * 4);
    (void)ws_size; (void)n_in; (void)in_sizes; (void)out_size;

    // params
    prep_params<<<NF + 2, HD, 0, stream>>>(emb, Ws, bs, lw, dW0, bW0, w2lw, b2lw);
    cvt_w_all<<<dim3(HD, 2), HD, 0, stream>>>(Ws, dW0, Wt, dW0t);

    // degrees, CSR build with inline norm + graph bounds in tail blocks
    hipMemsetAsync(deg, 0, NN * 4, stream);
    deg_kernel<<<(NE + 255) / 256, 256, 0, stream>>>(dst, deg, NE);
    chunk_sum_dinv<<<NCH, SCAN_CH, 0, stream>>>(deg, csum, dinv, selfn);
    chunk_apply<<<NCH, SCAN_CH, 0, stream>>>(deg, csum, row_s, cursor);
    csr_fill_gb<<<EB + (NG + 256) / 256, 256, 0, stream>>>(
        src, dst, dinv, cursor, ecol, enorm, batch, gstart);

    // layer 0: MFMA encoder -> buf1, aggregate (+fused BN partials) -> buf0
    encoder_mfma<<<dim3((NN + 127) / 128, 2), 256, 0, stream>>>(x, dW0t, bW0, buf1);
    gcn_aggregate<<<AGB, 1024, 0, stream>>>(
        buf1, selfn, bs, row_s, ecol, enorm, buf0, part);
    bn_scale<<<16, 256, 0, stream>>>(part, gam, bet, scale, shift);

    // layer 1: MFMA GEMM 128x256 (A read once) -> buf1, aggregate (+partials)
    gemm_mfma<<<(NN + 127) / 128, 512, 0, stream>>>(
        buf0, Wt, buf1, NN, scale, shift);
    gcn_aggregate<<<AGB, 1024, 0, stream>>>(
        buf1, selfn, bs + HD, row_s, ecol, enorm, buf0, part);
    bn_scale<<<16, 256, 0, stream>>>(part, gam + HD, bet + HD, scale, shift);

    // layer 2 (collapsed): z = relu_bn(buf0)@(W2 lw); fused agg+pool
    bn_dot<<<(NN * 64 + 255) / 256, 256, 0, stream>>>(buf0, scale, shift, w2lw, zbuf);
    pool_fused<<<(NG * 64 + 255) / 256, 256, 0, stream>>>(
        zbuf, selfn, b2lw, row_s, ecol, enorm, gstart, lb, out);
}

// Round 22
// 334.743 us; speedup vs baseline: 1.5725x; 1.5725x over previous
//
#include <hip/hip_runtime.h>
#include <hip/hip_bf16.h>

#define NN 100000      // nodes
#define NE 200000      // edges
#define NF 56          // atom feats
#define HD 256         // hidden
#define NG 2048        // graphs

#define SCAN_CH 512
#define NCH ((NN + SCAN_CH - 1) / SCAN_CH)   // 196 chunks
#define EB ((NE + 255) / 256)                // csr_fill edge blocks

#define AGB 6250       // aggregate blocks (16 nodes each, NN/16 exact)

typedef __bf16 bf16x8 __attribute__((ext_vector_type(8)));
typedef __bf16 bf16x4 __attribute__((ext_vector_type(4)));
typedef float  floatx4 __attribute__((ext_vector_type(4)));

// ---- param prep (merged): f<NF delta-row GEMM; f==NF base row; f==NF+1 w2lw -
__global__ void prep_params(const float* __restrict__ emb, const float* __restrict__ Ws,
                            const float* __restrict__ bs, const float* __restrict__ lw,
                            float* __restrict__ dW0, float* __restrict__ bW0,
                            float* __restrict__ w2lw, float* __restrict__ b2lw) {
    __shared__ float row[HD];
    int c = threadIdx.x;
    int f = blockIdx.x;
    if (f == NF + 1) {   // layer-2 collapse params
        const float* W2 = Ws + (size_t)2 * HD * HD;
        float acc = 0.f;
        for (int k = 0; k < HD; ++k) acc += W2[(size_t)c * HD + k] * lw[k];
        w2lw[c] = acc;
        row[c] = bs[2 * HD + c] * lw[c];
        __syncthreads();
        for (int off = 128; off > 0; off >>= 1) {
            if (c < off) row[c] += row[c + off];
            __syncthreads();
        }
        if (c == 0) *b2lw = row[0];
        return;
    }
    if (f < NF) {
        row[c] = emb[(f * 2 + 1) * HD + c] - emb[(f * 2 + 0) * HD + c];
    } else {
        float s = 0.f;
        for (int ff = 0; ff < NF; ++ff) s += emb[(ff * 2) * HD + c];
        row[c] = s;
    }
    __syncthreads();
    float acc = 0.f;
    for (int k = 0; k < HD; ++k) acc += row[k] * Ws[k * HD + c];   // W0
    if (f < NF) dW0[f * HD + c] = acc; else bW0[c] = acc;
}

// merged weight converts: l==0 -> Wt (layer-1 weights, Ws[1]); l==1 -> dW0t
__global__ void cvt_w_all(const float* __restrict__ Ws, const float* __restrict__ dW0,
                          __bf16* __restrict__ Wt, __bf16* __restrict__ dW0t) {
    int n = blockIdx.x, l = blockIdx.y, k = threadIdx.x;
    if (l == 0) {
        Wt[(size_t)n * HD + k] = (__bf16)Ws[(size_t)1 * HD * HD + (size_t)k * HD + n];
    } else if (k < 64) {
        dW0t[n * 64 + k] = (k < NF) ? (__bf16)dW0[k * HD + n] : (__bf16)0.f;
    }
}

// ---- degree ------------------------------------------------------------------
__global__ void deg_kernel(const int* __restrict__ dst, unsigned* __restrict__ deg, int E) {
    int e = blockIdx.x * blockDim.x + threadIdx.x;
    if (e < E) atomicAdd(&deg[dst[e]], 1u);
}

// merged: per-chunk degree sum (for scan) + dinv/selfn
__global__ void chunk_sum_dinv(const unsigned* __restrict__ deg, unsigned* __restrict__ csum,
                               float* __restrict__ dinv, float* __restrict__ selfn) {
    __shared__ unsigned s[SCAN_CH];
    int t = threadIdx.x;
    int base = blockIdx.x * SCAN_CH;
    unsigned v = (base + t < NN) ? deg[base + t] : 0u;
    s[t] = v;
    if (base + t < NN) {
        float d = (float)(v + 1u);   // +1 self loop
        dinv[base + t]  = rsqrtf(d);
        selfn[base + t] = 1.0f / d;
    }
    __syncthreads();
    for (int off = SCAN_CH / 2; off > 0; off >>= 1) {
        if (t < off) s[t] += s[t + off];
        __syncthreads();
    }
    if (t == 0) csum[blockIdx.x] = s[0];
}

// chunk_apply with INLINE scan of csum (each block re-scans 196 chunk sums)
__global__ void chunk_apply(const unsigned* __restrict__ deg, const unsigned* __restrict__ csum,
                            unsigned* __restrict__ row_start, unsigned* __restrict__ cursor) {
    __shared__ unsigned s[SCAN_CH];
    __shared__ unsigned cs[256];
    int t = threadIdx.x;
    if (t < 256) cs[t] = (t < NCH) ? csum[t] : 0u;
    __syncthreads();
    for (int off = 1; off < 256; off <<= 1) {
        unsigned add = (t < 256 && t >= off) ? cs[t - off] : 0u;
        __syncthreads();
        if (t < 256) cs[t] += add;
        __syncthreads();
    }
    unsigned chunk_base = (blockIdx.x == 0) ? 0u : cs[blockIdx.x - 1];

    int base = blockIdx.x * SCAN_CH;
    unsigned v = (base + t < NN) ? deg[base + t] : 0u;
    s[t] = v;
    __syncthreads();
    for (int off = 1; off < SCAN_CH; off <<= 1) {
        unsigned add = (t >= off) ? s[t - off] : 0u;
        __syncthreads();
        s[t] += add;
        __syncthreads();
    }
    if (base + t < NN) {
        unsigned rs = chunk_base + s[t] - v;   // exclusive scan value
        row_start[base + t] = rs;
        cursor[base + t] = rs;
    }
    if (blockIdx.x == 0 && t == 0) row_start[NN] = NE;
}

// csr_fill (inline norm) + graph_bounds merged into the tail blocks
__global__ void csr_fill_gb(const int* __restrict__ src, const int* __restrict__ dst,
                            const float* __restrict__ dinv, unsigned* __restrict__ cursor,
                            int* __restrict__ ecol, float* __restrict__ enorm,
                            const int* __restrict__ batch, unsigned* __restrict__ gstart) {
    int t = threadIdx.x;
    if (blockIdx.x < EB) {
        int e = blockIdx.x * 256 + t;
        if (e < NE) {
            int s = src[e], d = dst[e];
            unsigned pos = atomicAdd(&cursor[d], 1u);
            ecol[pos] = s;
            enorm[pos] = dinv[s] * dinv[d];
        }
    } else {
        int g = (blockIdx.x - EB) * 256 + t;
        if (g <= NG) {
            int lo = 0, hi = NN;
            while (lo < hi) {
                int mid = (lo + hi) >> 1;
                if (batch[mid] < g) lo = mid + 1; else hi = mid;
            }
            gstart[g] = (unsigned)lo;
        }
    }
}

// ---- MFMA encoder: hw0 = X @ dW0t^T + bW0, X binary [NN,56] pad K->64 -------
#define ELSTR 68
__global__ void __launch_bounds__(256) encoder_mfma(const int* __restrict__ x,
                                                    const __bf16* __restrict__ dW0t,
                                                    const float* __restrict__ bW0,
                                                    __bf16* __restrict__ C) {
    __shared__ __bf16 sA[128 * ELSTR];   // 17408 B
    __shared__ __bf16 sB[128 * ELSTR];   // 17408 B
    int t = threadIdx.x;
    int m0 = blockIdx.x * 128;
    int n0 = blockIdx.y * 128;
    int lane = t & 63, w = t >> 6;
    int quad = lane >> 4, l16 = lane & 15;
    int mw = (w & 1) * 64, nw = (w >> 1) * 64;

    {
        int r = t >> 1;
        int kh = (t & 1) * 32;
        int row = m0 + r;
        int nreal = (kh == 0) ? 32 : 24;
        #pragma unroll
        for (int j = 0; j < 8; ++j) {
            bf16x4 b;
            if (row < NN && j * 4 < nreal) {
                int4 iv = *(const int4*)&x[(size_t)row * NF + kh + j * 4];
                b[0] = (__bf16)(float)iv.x;
                b[1] = (__bf16)(float)iv.y;
                b[2] = (__bf16)(float)iv.z;
                b[3] = (__bf16)(float)iv.w;
            } else {
                b[0] = b[1] = b[2] = b[3] = (__bf16)0.f;
            }
            *(bf16x4*)&sA[r * ELSTR + kh + j * 4] = b;
        }
    }
    {
        int bn = t >> 1;
        int kh = (t & 1) * 32;
        #pragma unroll
        for (int j = 0; j < 4; ++j) {
            bf16x8 v = *(const bf16x8*)&dW0t[(size_t)(n0 + bn) * 64 + kh + j * 8];
            *(bf16x8*)&sB[bn * ELSTR + kh + j * 8] = v;
        }
    }
    __syncthreads();

    floatx4 acc[4][4] = {};
    #pragma unroll
    for (int s = 0; s < 2; ++s) {
        bf16x8 af[4], bfr[4];
        #pragma unroll
        for (int i = 0; i < 4; ++i)
            af[i] = *(const bf16x8*)&sA[(mw + i * 16 + l16) * ELSTR + s * 32 + quad * 8];
        #pragma unroll
        for (int i = 0; i < 4; ++i)
            bfr[i] = *(const bf16x8*)&sB[(nw + i * 16 + l16) * ELSTR + s * 32 + quad * 8];
        #pragma unroll
        for (int mi = 0; mi < 4; ++mi)
            #pragma unroll
            for (int ni = 0; ni < 4; ++ni)
                acc[mi][ni] = __builtin_amdgcn_mfma_f32_16x16x32_bf16(
                    af[mi], bfr[ni], acc[mi][ni], 0, 0, 0);
    }

    float bw[4];
    #pragma unroll
    for (int ni = 0; ni < 4; ++ni) bw[ni] = bW0[n0 + nw + ni * 16 + l16];
    #pragma unroll
    for (int mi = 0; mi < 4; ++mi) {
        #pragma unroll
        for (int r = 0; r < 4; ++r) {
            int row = m0 + mw + mi * 16 + quad * 4 + r;
            if (row < NN) {
                #pragma unroll
                for (int ni = 0; ni < 4; ++ni)
                    C[(size_t)row * HD + n0 + nw + ni * 16 + l16] =
                        (__bf16)(acc[mi][ni][r] + bw[ni]);
            }
        }
    }
}

// ---- bf16 MFMA GEMM: 128x256 tile (full N), 512 thr / 8 waves (2m x 4n) -----
#define LSTR 36
__global__ void __launch_bounds__(512) gemm_mfma(const __bf16* __restrict__ A,
                                                 const __bf16* __restrict__ Wt,
                                                 __bf16* __restrict__ C, int M,
                                                 const float* __restrict__ ascale,
                                                 const float* __restrict__ ashift) {
    __shared__ __bf16 sA[128 * LSTR];   //  9216 B
    __shared__ __bf16 sB[256 * LSTR];   // 18432 B
    int t = threadIdx.x;                // 0..511
    int m0 = blockIdx.x * 128;
    int lane = t & 63, w = t >> 6;      // 8 waves
    int quad = lane >> 4, l16 = lane & 15;
    int mw = (w & 1) * 64;
    int nw = (w >> 1) * 64;             // 0,64,128,192

    int ar = t >> 2;          // A-stage row 0..127
    int ak = (t & 3) * 8;     // 16-B k-offset within 32-tile
    int bn = t >> 1;          // B-stage LDS row (n), 0..255
    int bk = (t & 1) * 16;    // k-offset (two bf16x8)

    auto ldA = [&](int k0, bf16x8& pa) {
        float4 s0 = *(const float4*)&ascale[k0 + ak];
        float4 s1 = *(const float4*)&ascale[k0 + ak + 4];
        float4 h0 = *(const float4*)&ashift[k0 + ak];
        float4 h1 = *(const float4*)&ashift[k0 + ak + 4];
        int row = m0 + ar;
        bf16x8 a = {};
        if (row < M) a = *(const bf16x8*)&A[(size_t)row * HD + k0 + ak];
        bf16x8 b;
        b[0] = (__bf16)fmaxf((float)a[0] * s0.x + h0.x, 0.f);
        b[1] = (__bf16)fmaxf((float)a[1] * s0.y + h0.y, 0.f);
        b[2] = (__bf16)fmaxf((float)a[2] * s0.z + h0.z, 0.f);
        b[3] = (__bf16)fmaxf((float)a[3] * s0.w + h0.w, 0.f);
        b[4] = (__bf16)fmaxf((float)a[4] * s1.x + h1.x, 0.f);
        b[5] = (__bf16)fmaxf((float)a[5] * s1.y + h1.y, 0.f);
        b[6] = (__bf16)fmaxf((float)a[6] * s1.z + h1.z, 0.f);
        b[7] = (__bf16)fmaxf((float)a[7] * s1.w + h1.w, 0.f);
        pa = b;
    };
    auto ldB = [&](int k0, bf16x8 pb[2]) {
        #pragma unroll
        for (int j = 0; j < 2; ++j)
            pb[j] = *(const bf16x8*)&Wt[(size_t)bn * HD + k0 + bk + j * 8];
    };

    bf16x8 pa, pb[2];
    ldA(0, pa);
    ldB(0, pb);

    floatx4 acc[4][4] = {};

    for (int k0 = 0; k0 < 256; k0 += 32) {
        *(bf16x8*)&sA[ar * LSTR + ak] = pa;
        *(bf16x8*)&sB[bn * LSTR + bk]     = pb[0];
        *(bf16x8*)&sB[bn * LSTR + bk + 8] = pb[1];
        __syncthreads();

        if (k0 + 32 < 256) {
            ldA(k0 + 32, pa);
            ldB(k0 + 32, pb);
        }

        bf16x8 af[4], bfr[4];
        #pragma unroll
        for (int i = 0; i < 4; ++i)
            af[i] = *(const bf16x8*)&sA[(mw + i * 16 + l16) * LSTR + quad * 8];
        #pragma unroll
        for (int i = 0; i < 4; ++i)
            bfr[i] = *(const bf16x8*)&sB[(nw + i * 16 + l16) * LSTR + quad * 8];
        #pragma unroll
        for (int mi = 0; mi < 4; ++mi)
            #pragma unroll
            for (int ni = 0; ni < 4; ++ni)
                acc[mi][ni] = __builtin_amdgcn_mfma_f32_16x16x32_bf16(
                    af[mi], bfr[ni], acc[mi][ni], 0, 0, 0);
        __syncthreads();
    }

    #pragma unroll
    for (int mi = 0; mi < 4; ++mi) {
        #pragma unroll
        for (int r = 0; r < 4; ++r) {
            int row = m0 + mw + mi * 16 + quad * 4 + r;
            if (row < M) {
                #pragma unroll
                for (int ni = 0; ni < 4; ++ni)
                    C[(size_t)row * HD + nw + ni * 16 + l16] = (__bf16)acc[mi][ni][r];
            }
        }
    }
}

// ---- CSR gather-aggregate + fused BN partials (1024 thr = 16 waves/nodes) ---
__global__ void __launch_bounds__(1024) gcn_aggregate(const __bf16* __restrict__ hw,
                                                      const float* __restrict__ selfn,
                                                      const float* __restrict__ bias,
                                                      const unsigned* __restrict__ row_start,
                                                      const int* __restrict__ ecol,
                                                      const float* __restrict__ enorm,
                                                      __bf16* __restrict__ agg,
                                                      float* __restrict__ part) {
    __shared__ float4 ssum[16][64];   // 16 KB
    __shared__ float4 sss[16][64];    // 16 KB
    int t = threadIdx.x;
    int l = t & 63, w = t >> 6;       // 16 waves
    int n = blockIdx.x * 16 + w;      // grid == NN/16 exactly
    int c4 = l * 4;
    float s = selfn[n];
    bf16x4 hv = *(const bf16x4*)&hw[(size_t)n * HD + c4];
    float4 acc;
    acc.x = (float)hv[0] * s + bias[c4 + 0];
    acc.y = (float)hv[1] * s + bias[c4 + 1];
    acc.z = (float)hv[2] * s + bias[c4 + 2];
    acc.w = (float)hv[3] * s + bias[c4 + 3];
    unsigned e0 = row_start[n], e1 = row_start[n + 1];
    unsigned e = e0;
    for (; e + 4 <= e1; e += 4) {
        int sv0 = ecol[e], sv1 = ecol[e + 1], sv2 = ecol[e + 2], sv3 = ecol[e + 3];
        float nm0 = enorm[e], nm1 = enorm[e + 1], nm2 = enorm[e + 2], nm3 = enorm[e + 3];
        bf16x4 u0 = *(const bf16x4*)&hw[(size_t)sv0 * HD + c4];
        bf16x4 u1 = *(const bf16x4*)&hw[(size_t)sv1 * HD + c4];
        bf16x4 u2 = *(const bf16x4*)&hw[(size_t)sv2 * HD + c4];
        bf16x4 u3 = *(const bf16x4*)&hw[(size_t)sv3 * HD + c4];
        acc.x += (float)u0[0] * nm0 + (float)u1[0] * nm1 + (float)u2[0] * nm2 + (float)u3[0] * nm3;
        acc.y += (float)u0[1] * nm0 + (float)u1[1] * nm1 + (float)u2[1] * nm2 + (float)u3[1] * nm3;
        acc.z += (float)u0[2] * nm0 + (float)u1[2] * nm1 + (float)u2[2] * nm2 + (float)u3[2] * nm3;
        acc.w += (float)u0[3] * nm0 + (float)u1[3] * nm1 + (float)u2[3] * nm2 + (float)u3[3] * nm3;
    }
    for (; e + 2 <= e1; e += 2) {
        int sv0 = ecol[e], sv1 = ecol[e + 1];
        float nm0 = enorm[e], nm1 = enorm[e + 1];
        bf16x4 u0 = *(const bf16x4*)&hw[(size_t)sv0 * HD + c4];
        bf16x4 u1 = *(const bf16x4*)&hw[(size_t)sv1 * HD + c4];
        acc.x += (float)u0[0] * nm0 + (float)u1[0] * nm1;
        acc.y += (float)u0[1] * nm0 + (float)u1[1] * nm1;
        acc.z += (float)u0[2] * nm0 + (float)u1[2] * nm1;
        acc.w += (float)u0[3] * nm0 + (float)u1[3] * nm1;
    }
    if (e < e1) {
        int sv = ecol[e];
        float nm = enorm[e];
        bf16x4 u = *(const bf16x4*)&hw[(size_t)sv * HD + c4];
        acc.x += (float)u[0] * nm;
        acc.y += (float)u[1] * nm;
        acc.z += (float)u[2] * nm;
        acc.w += (float)u[3] * nm;
    }
    bf16x4 o;
    o[0] = (__bf16)acc.x; o[1] = (__bf16)acc.y;
    o[2] = (__bf16)acc.z; o[3] = (__bf16)acc.w;
    *(bf16x4*)&agg[(size_t)n * HD + c4] = o;

    if (part) {
        ssum[w][l] = acc;
        sss[w][l]  = make_float4(acc.x * acc.x, acc.y * acc.y, acc.z * acc.z, acc.w * acc.w);
        __syncthreads();
        if (w == 0) {
            float4 a = ssum[0][l], q = sss[0][l];
            #pragma unroll
            for (int i = 1; i < 16; ++i) {
                float4 b = ssum[i][l], r = sss[i][l];
                a.x += b.x; a.y += b.y; a.z += b.z; a.w += b.w;
                q.x += r.x; q.y += r.y; q.z += r.z; q.w += r.w;
            }
            *(float4*)&part[(size_t)blockIdx.x * 512 + c4]       = a;
            *(float4*)&part[(size_t)blockIdx.x * 512 + 256 + c4] = q;
        }
    }
}

// ---- bn_scale: 256 blocks, block c reduces column c over AGB row-blocks -----
__global__ void __launch_bounds__(256) bn_scale(const float* __restrict__ part,
                                                const float* __restrict__ gamma,
                                                const float* __restrict__ beta,
                                                float* __restrict__ scale,
                                                float* __restrict__ shift) {
    __shared__ float rs[256], rq[256];
    int t = threadIdx.x;
    int c = blockIdx.x;
    float s = 0.f, q = 0.f;
    for (int j = t; j < AGB; j += 256) {
        s += part[(size_t)j * 512 + c];
        q += part[(size_t)j * 512 + 256 + c];
    }
    rs[t] = s; rq[t] = q;
    __syncthreads();
    for (int off = 128; off > 0; off >>= 1) {
        if (t < off) { rs[t] += rs[t + off]; rq[t] += rq[t + off]; }
        __syncthreads();
    }
    if (t == 0) {
        const float inv_n = 1.0f / (float)NN;
        float mu  = rs[0] * inv_n;
        float var = rq[0] * inv_n - mu * mu;
        float rstd = rsqrtf(var + 1e-5f);
        float sc = gamma[c] * rstd;
        scale[c] = sc;
        shift[c] = beta[c] - mu * sc;
    }
}

// ---- layer-2 collapse: z[n] = relu_bn(buf0[n]) . w2lw  (one wave per node) --
__global__ void __launch_bounds__(256) bn_dot(const __bf16* __restrict__ h,
                                              const float* __restrict__ scale,
                                              const float* __restrict__ shift,
                                              const float* __restrict__ w2lw,
                                              float* __restrict__ z) {
    int tid = blockIdx.x * 256 + threadIdx.x;
    int n = tid >> 6;
    if (n >= NN) return;
    int l = tid & 63;
    int c4 = l * 4;
    bf16x4 a = *(const bf16x4*)&h[(size_t)n * HD + c4];
    float4 sc = *(const float4*)&scale[c4];
    float4 sh = *(const float4*)&shift[c4];
    float4 wv = *(const float4*)&w2lw[c4];
    float d = fmaxf((float)a[0] * sc.x + sh.x, 0.f) * wv.x
            + fmaxf((float)a[1] * sc.y + sh.y, 0.f) * wv.y
            + fmaxf((float)a[2] * sc.z + sh.z, 0.f) * wv.z
            + fmaxf((float)a[3] * sc.w + sh.w, 0.f) * wv.w;
    #pragma unroll
    for (int off = 32; off > 0; off >>= 1) d += __shfl_down(d, off, 64);
    if (l == 0) z[n] = d;
}

// ---- fused final: per-graph wave; lanes stride nodes; scalar edge loop ------
__global__ void __launch_bounds__(256) pool_fused(const float* __restrict__ z,
                                                  const float* __restrict__ selfn,
                                                  const float* __restrict__ b2lw,
                                                  const unsigned* __restrict__ row_start,
                                                  const int* __restrict__ ecol,
                                                  const float* __restrict__ enorm,
                                                  const unsigned* __restrict__ gstart,
                                                  const float* __restrict__ lb,
                                                  float* __restrict__ out) {
    int tid = blockIdx.x * 256 + threadIdx.x;
    int g = tid >> 6;
    if (g >= NG) return;
    int l = tid & 63;
    unsigned s0 = gstart[g], s1 = gstart[g + 1];
    float bb = *b2lw;
    float s = 0.f;
    for (unsigned i = s0 + l; i < s1; i += 64) {
        float d = selfn[i] * z[i] + bb;
        unsigned e0 = row_start[i], e1 = row_start[i + 1];
        for (unsigned e = e0; e < e1; ++e)
            d += enorm[e] * z[ecol[e]];
        s += d;
    }
    #pragma unroll
    for (int off = 32; off > 0; off >>= 1) s += __shfl_down(s, off, 64);
    if (l == 0) out[g] = s / fmaxf((float)(s1 - s0), 1.0f) + lb[0];
}

// ---- driver -----------------------------------------------------------------
extern "C" void kernel_launch(void* const* d_in, const int* in_sizes, int n_in,
                              void* d_out, int out_size, void* d_ws, size_t ws_size,
                              hipStream_t stream) {
    const int*   x     = (const int*)d_in[0];
    const int*   ei    = (const int*)d_in[1];
    const int*   batch = (const int*)d_in[2];
    const float* emb   = (const float*)d_in[3];
    const float* Ws    = (const float*)d_in[4];
    const float* bs    = (const float*)d_in[5];
    const float* gam   = (const float*)d_in[6];
    const float* bet   = (const float*)d_in[7];
    const float* lw    = (const float*)d_in[8];
    const float* lb    = (const float*)d_in[9];
    float* out = (float*)d_out;

    const int* src = ei;
    const int* dst = ei + NE;

    // workspace carve-up (256-B aligned)
    char* p = (char*)d_ws;
    size_t off = 0;
    auto carve = [&](size_t bytes) { void* r = p + off; off = (off + bytes + 255) & ~(size_t)255; return r; };
    __bf16*   buf0   = (__bf16*)carve((size_t)NN * HD * 2);   // agg (bf16)
    __bf16*   buf1   = (__bf16*)carve((size_t)NN * HD * 2);   // hw  (bf16)
    float*    dW0    = (float*)carve(NF * HD * 4);
    float*    bW0    = (float*)carve(HD * 4);
    __bf16*   dW0t   = (__bf16*)carve(HD * 64 * 2);
    __bf16*   Wt     = (__bf16*)carve((size_t)HD * HD * 2);   // layer-1 only
    float*    w2lw   = (float*)carve(HD * 4);
    float*    b2lw   = (float*)carve(256);
    unsigned* deg    = (unsigned*)carve(NN * 4);
    float*    dinv   = (float*)carve(NN * 4);
    float*    selfn  = (float*)carve(NN * 4);
    unsigned* csum   = (unsigned*)carve(256 * 4);
    unsigned* row_s  = (unsigned*)carve((NN + 1) * 4);
    unsigned* cursor = (unsigned*)carve(NN * 4);
    int*      ecol   = (int*)carve(NE * 4);
    float*    enorm  = (float*)carve(NE * 4);
    float*    part   = (float*)carve((size_t)AGB * 512 * 4);   // 12.8 MB
    float*    scale  = (float*)carve(HD * 4);
    float*    shift  = (float*)carve(HD * 4);
    unsigned* gstart = (unsigned*)carve((NG + 1) * 4);
    float*    zbuf   = (float*)carve(NN * 4);
    (void)ws_size; (void)n_in; (void)in_sizes; (void)out_size;

    // params
    prep_params<<<NF + 2, HD, 0, stream>>>(emb, Ws, bs, lw, dW0, bW0, w2lw, b2lw);
    cvt_w_all<<<dim3(HD, 2), HD, 0, stream>>>(Ws, dW0, Wt, dW0t);

    // degrees, CSR build with inline norm + graph bounds in tail blocks
    hipMemsetAsync(deg, 0, NN * 4, stream);
    deg_kernel<<<(NE + 255) / 256, 256, 0, stream>>>(dst, deg, NE);
    chunk_sum_dinv<<<NCH, SCAN_CH, 0, stream>>>(deg, csum, dinv, selfn);
    chunk_apply<<<NCH, SCAN_CH, 0, stream>>>(deg, csum, row_s, cursor);
    csr_fill_gb<<<EB + (NG + 256) / 256, 256, 0, stream>>>(
        src, dst, dinv, cursor, ecol, enorm, batch, gstart);

    // layer 0: MFMA encoder -> buf1, aggregate (+fused BN partials) -> buf0
    encoder_mfma<<<dim3((NN + 127) / 128, 2), 256, 0, stream>>>(x, dW0t, bW0, buf1);
    gcn_aggregate<<<AGB, 1024, 0, stream>>>(
        buf1, selfn, bs, row_s, ecol, enorm, buf0, part);
    bn_scale<<<HD, 256, 0, stream>>>(part, gam, bet, scale, shift);

    // layer 1: MFMA GEMM 128x256 (A read once) -> buf1, aggregate (+partials)
    gemm_mfma<<<(NN + 127) / 128, 512, 0, stream>>>(
        buf0, Wt, buf1, NN, scale, shift);
    gcn_aggregate<<<AGB, 1024, 0, stream>>>(
        buf1, selfn, bs + HD, row_s, ecol, enorm, buf0, part);
    bn_scale<<<HD, 256, 0, stream>>>(part, gam + HD, bet + HD, scale, shift);

    // layer 2 (collapsed): z = relu_bn(buf0)@(W2 lw); fused agg+pool
    bn_dot<<<(NN * 64 + 255) / 256, 256, 0, stream>>>(buf0, scale, shift, w2lw, zbuf);
    pool_fused<<<(NG * 64 + 255) / 256, 256, 0, stream>>>(
        zbuf, selfn, b2lw, row_s, ecol, enorm, gstart, lb, out);
}

// Round 23
// 317.632 us; speedup vs baseline: 1.6572x; 1.0539x over previous
//
#include <hip/hip_runtime.h>
#include <hip/hip_bf16.h>

#define NN 100000      // nodes
#define NE 200000      // edges
#define NF 56          // atom feats
#define HD 256         // hidden
#define NG 2048        // graphs

#define SCAN_CH 512
#define NCH ((NN + SCAN_CH - 1) / SCAN_CH)   // 196 chunks
#define EB ((NE + 255) / 256)                // csr_fill edge blocks

#define PB 2048        // bn_partial blocks (4 MB partials)

typedef __bf16 bf16x8 __attribute__((ext_vector_type(8)));
typedef __bf16 bf16x4 __attribute__((ext_vector_type(4)));
typedef float  floatx4 __attribute__((ext_vector_type(4)));

// ---- param prep (merged): f<NF delta-row GEMM; f==NF base row; f==NF+1 w2lw -
__global__ void prep_params(const float* __restrict__ emb, const float* __restrict__ Ws,
                            const float* __restrict__ bs, const float* __restrict__ lw,
                            float* __restrict__ dW0, float* __restrict__ bW0,
                            float* __restrict__ w2lw, float* __restrict__ b2lw) {
    __shared__ float row[HD];
    int c = threadIdx.x;
    int f = blockIdx.x;
    if (f == NF + 1) {   // layer-2 collapse params
        const float* W2 = Ws + (size_t)2 * HD * HD;
        float acc = 0.f;
        for (int k = 0; k < HD; ++k) acc += W2[(size_t)c * HD + k] * lw[k];
        w2lw[c] = acc;
        row[c] = bs[2 * HD + c] * lw[c];
        __syncthreads();
        for (int off = 128; off > 0; off >>= 1) {
            if (c < off) row[c] += row[c + off];
            __syncthreads();
        }
        if (c == 0) *b2lw = row[0];
        return;
    }
    if (f < NF) {
        row[c] = emb[(f * 2 + 1) * HD + c] - emb[(f * 2 + 0) * HD + c];
    } else {
        float s = 0.f;
        for (int ff = 0; ff < NF; ++ff) s += emb[(ff * 2) * HD + c];
        row[c] = s;
    }
    __syncthreads();
    float acc = 0.f;
    for (int k = 0; k < HD; ++k) acc += row[k] * Ws[k * HD + c];   // W0
    if (f < NF) dW0[f * HD + c] = acc; else bW0[c] = acc;
}

// merged weight converts: l==0 -> Wt (layer-1 weights, Ws[1]); l==1 -> dW0t
__global__ void cvt_w_all(const float* __restrict__ Ws, const float* __restrict__ dW0,
                          __bf16* __restrict__ Wt, __bf16* __restrict__ dW0t) {
    int n = blockIdx.x, l = blockIdx.y, k = threadIdx.x;
    if (l == 0) {
        Wt[(size_t)n * HD + k] = (__bf16)Ws[(size_t)1 * HD * HD + (size_t)k * HD + n];
    } else if (k < 64) {
        dW0t[n * 64 + k] = (k < NF) ? (__bf16)dW0[k * HD + n] : (__bf16)0.f;
    }
}

// ---- degree ------------------------------------------------------------------
__global__ void deg_kernel(const int* __restrict__ dst, unsigned* __restrict__ deg, int E) {
    int e = blockIdx.x * blockDim.x + threadIdx.x;
    if (e < E) atomicAdd(&deg[dst[e]], 1u);
}

// merged: per-chunk degree sum (for scan) + dinv/selfn
__global__ void chunk_sum_dinv(const unsigned* __restrict__ deg, unsigned* __restrict__ csum,
                               float* __restrict__ dinv, float* __restrict__ selfn) {
    __shared__ unsigned s[SCAN_CH];
    int t = threadIdx.x;
    int base = blockIdx.x * SCAN_CH;
    unsigned v = (base + t < NN) ? deg[base + t] : 0u;
    s[t] = v;
    if (base + t < NN) {
        float d = (float)(v + 1u);   // +1 self loop
        dinv[base + t]  = rsqrtf(d);
        selfn[base + t] = 1.0f / d;
    }
    __syncthreads();
    for (int off = SCAN_CH / 2; off > 0; off >>= 1) {
        if (t < off) s[t] += s[t + off];
        __syncthreads();
    }
    if (t == 0) csum[blockIdx.x] = s[0];
}

// chunk_apply with INLINE scan of csum (each block re-scans 196 chunk sums)
__global__ void chunk_apply(const unsigned* __restrict__ deg, const unsigned* __restrict__ csum,
                            unsigned* __restrict__ row_start, unsigned* __restrict__ cursor) {
    __shared__ unsigned s[SCAN_CH];
    __shared__ unsigned cs[256];
    int t = threadIdx.x;
    if (t < 256) cs[t] = (t < NCH) ? csum[t] : 0u;
    __syncthreads();
    for (int off = 1; off < 256; off <<= 1) {
        unsigned add = (t < 256 && t >= off) ? cs[t - off] : 0u;
        __syncthreads();
        if (t < 256) cs[t] += add;
        __syncthreads();
    }
    unsigned chunk_base = (blockIdx.x == 0) ? 0u : cs[blockIdx.x - 1];

    int base = blockIdx.x * SCAN_CH;
    unsigned v = (base + t < NN) ? deg[base + t] : 0u;
    s[t] = v;
    __syncthreads();
    for (int off = 1; off < SCAN_CH; off <<= 1) {
        unsigned add = (t >= off) ? s[t - off] : 0u;
        __syncthreads();
        s[t] += add;
        __syncthreads();
    }
    if (base + t < NN) {
        unsigned rs = chunk_base + s[t] - v;   // exclusive scan value
        row_start[base + t] = rs;
        cursor[base + t] = rs;
    }
    if (blockIdx.x == 0 && t == 0) row_start[NN] = NE;
}

// csr_fill (inline norm) + graph_bounds merged into the tail blocks
__global__ void csr_fill_gb(const int* __restrict__ src, const int* __restrict__ dst,
                            const float* __restrict__ dinv, unsigned* __restrict__ cursor,
                            int* __restrict__ ecol, float* __restrict__ enorm,
                            const int* __restrict__ batch, unsigned* __restrict__ gstart) {
    int t = threadIdx.x;
    if (blockIdx.x < EB) {
        int e = blockIdx.x * 256 + t;
        if (e < NE) {
            int s = src[e], d = dst[e];
            unsigned pos = atomicAdd(&cursor[d], 1u);
            ecol[pos] = s;
            enorm[pos] = dinv[s] * dinv[d];
        }
    } else {
        int g = (blockIdx.x - EB) * 256 + t;
        if (g <= NG) {
            int lo = 0, hi = NN;
            while (lo < hi) {
                int mid = (lo + hi) >> 1;
                if (batch[mid] < g) lo = mid + 1; else hi = mid;
            }
            gstart[g] = (unsigned)lo;
        }
    }
}

// ---- MFMA encoder: hw0 = X @ dW0t^T + bW0, X binary [NN,56] pad K->64 -------
#define ELSTR 68
__global__ void __launch_bounds__(256) encoder_mfma(const int* __restrict__ x,
                                                    const __bf16* __restrict__ dW0t,
                                                    const float* __restrict__ bW0,
                                                    __bf16* __restrict__ C) {
    __shared__ __bf16 sA[128 * ELSTR];   // 17408 B
    __shared__ __bf16 sB[128 * ELSTR];   // 17408 B
    int t = threadIdx.x;
    int m0 = blockIdx.x * 128;
    int n0 = blockIdx.y * 128;
    int lane = t & 63, w = t >> 6;
    int quad = lane >> 4, l16 = lane & 15;
    int mw = (w & 1) * 64, nw = (w >> 1) * 64;

    {
        int r = t >> 1;
        int kh = (t & 1) * 32;
        int row = m0 + r;
        int nreal = (kh == 0) ? 32 : 24;
        #pragma unroll
        for (int j = 0; j < 8; ++j) {
            bf16x4 b;
            if (row < NN && j * 4 < nreal) {
                int4 iv = *(const int4*)&x[(size_t)row * NF + kh + j * 4];
                b[0] = (__bf16)(float)iv.x;
                b[1] = (__bf16)(float)iv.y;
                b[2] = (__bf16)(float)iv.z;
                b[3] = (__bf16)(float)iv.w;
            } else {
                b[0] = b[1] = b[2] = b[3] = (__bf16)0.f;
            }
            *(bf16x4*)&sA[r * ELSTR + kh + j * 4] = b;
        }
    }
    {
        int bn = t >> 1;
        int kh = (t & 1) * 32;
        #pragma unroll
        for (int j = 0; j < 4; ++j) {
            bf16x8 v = *(const bf16x8*)&dW0t[(size_t)(n0 + bn) * 64 + kh + j * 8];
            *(bf16x8*)&sB[bn * ELSTR + kh + j * 8] = v;
        }
    }
    __syncthreads();

    floatx4 acc[4][4] = {};
    #pragma unroll
    for (int s = 0; s < 2; ++s) {
        bf16x8 af[4], bfr[4];
        #pragma unroll
        for (int i = 0; i < 4; ++i)
            af[i] = *(const bf16x8*)&sA[(mw + i * 16 + l16) * ELSTR + s * 32 + quad * 8];
        #pragma unroll
        for (int i = 0; i < 4; ++i)
            bfr[i] = *(const bf16x8*)&sB[(nw + i * 16 + l16) * ELSTR + s * 32 + quad * 8];
        #pragma unroll
        for (int mi = 0; mi < 4; ++mi)
            #pragma unroll
            for (int ni = 0; ni < 4; ++ni)
                acc[mi][ni] = __builtin_amdgcn_mfma_f32_16x16x32_bf16(
                    af[mi], bfr[ni], acc[mi][ni], 0, 0, 0);
    }

    float bw[4];
    #pragma unroll
    for (int ni = 0; ni < 4; ++ni) bw[ni] = bW0[n0 + nw + ni * 16 + l16];
    #pragma unroll
    for (int mi = 0; mi < 4; ++mi) {
        #pragma unroll
        for (int r = 0; r < 4; ++r) {
            int row = m0 + mw + mi * 16 + quad * 4 + r;
            if (row < NN) {
                #pragma unroll
                for (int ni = 0; ni < 4; ++ni)
                    C[(size_t)row * HD + n0 + nw + ni * 16 + l16] =
                        (__bf16)(acc[mi][ni][r] + bw[ni]);
            }
        }
    }
}

// ---- bf16 MFMA GEMM: 128x256 tile (full N), 512 thr / 8 waves (2m x 4n) -----
#define LSTR 36
__global__ void __launch_bounds__(512) gemm_mfma(const __bf16* __restrict__ A,
                                                 const __bf16* __restrict__ Wt,
                                                 __bf16* __restrict__ C, int M,
                                                 const float* __restrict__ ascale,
                                                 const float* __restrict__ ashift) {
    __shared__ __bf16 sA[128 * LSTR];   //  9216 B
    __shared__ __bf16 sB[256 * LSTR];   // 18432 B
    int t = threadIdx.x;                // 0..511
    int m0 = blockIdx.x * 128;
    int lane = t & 63, w = t >> 6;      // 8 waves
    int quad = lane >> 4, l16 = lane & 15;
    int mw = (w & 1) * 64;
    int nw = (w >> 1) * 64;             // 0,64,128,192

    int ar = t >> 2;          // A-stage row 0..127
    int ak = (t & 3) * 8;     // 16-B k-offset within 32-tile
    int bn = t >> 1;          // B-stage LDS row (n), 0..255
    int bk = (t & 1) * 16;    // k-offset (two bf16x8)

    auto ldA = [&](int k0, bf16x8& pa) {
        float4 s0 = *(const float4*)&ascale[k0 + ak];
        float4 s1 = *(const float4*)&ascale[k0 + ak + 4];
        float4 h0 = *(const float4*)&ashift[k0 + ak];
        float4 h1 = *(const float4*)&ashift[k0 + ak + 4];
        int row = m0 + ar;
        bf16x8 a = {};
        if (row < M) a = *(const bf16x8*)&A[(size_t)row * HD + k0 + ak];
        bf16x8 b;
        b[0] = (__bf16)fmaxf((float)a[0] * s0.x + h0.x, 0.f);
        b[1] = (__bf16)fmaxf((float)a[1] * s0.y + h0.y, 0.f);
        b[2] = (__bf16)fmaxf((float)a[2] * s0.z + h0.z, 0.f);
        b[3] = (__bf16)fmaxf((float)a[3] * s0.w + h0.w, 0.f);
        b[4] = (__bf16)fmaxf((float)a[4] * s1.x + h1.x, 0.f);
        b[5] = (__bf16)fmaxf((float)a[5] * s1.y + h1.y, 0.f);
        b[6] = (__bf16)fmaxf((float)a[6] * s1.z + h1.z, 0.f);
        b[7] = (__bf16)fmaxf((float)a[7] * s1.w + h1.w, 0.f);
        pa = b;
    };
    auto ldB = [&](int k0, bf16x8 pb[2]) {
        #pragma unroll
        for (int j = 0; j < 2; ++j)
            pb[j] = *(const bf16x8*)&Wt[(size_t)bn * HD + k0 + bk + j * 8];
    };

    bf16x8 pa, pb[2];
    ldA(0, pa);
    ldB(0, pb);

    floatx4 acc[4][4] = {};

    for (int k0 = 0; k0 < 256; k0 += 32) {
        *(bf16x8*)&sA[ar * LSTR + ak] = pa;
        *(bf16x8*)&sB[bn * LSTR + bk]     = pb[0];
        *(bf16x8*)&sB[bn * LSTR + bk + 8] = pb[1];
        __syncthreads();

        if (k0 + 32 < 256) {
            ldA(k0 + 32, pa);
            ldB(k0 + 32, pb);
        }

        bf16x8 af[4], bfr[4];
        #pragma unroll
        for (int i = 0; i < 4; ++i)
            af[i] = *(const bf16x8*)&sA[(mw + i * 16 + l16) * LSTR + quad * 8];
        #pragma unroll
        for (int i = 0; i < 4; ++i)
            bfr[i] = *(const bf16x8*)&sB[(nw + i * 16 + l16) * LSTR + quad * 8];
        #pragma unroll
        for (int mi = 0; mi < 4; ++mi)
            #pragma unroll
            for (int ni = 0; ni < 4; ++ni)
                acc[mi][ni] = __builtin_amdgcn_mfma_f32_16x16x32_bf16(
                    af[mi], bfr[ni], acc[mi][ni], 0, 0, 0);
        __syncthreads();
    }

    #pragma unroll
    for (int mi = 0; mi < 4; ++mi) {
        #pragma unroll
        for (int r = 0; r < 4; ++r) {
            int row = m0 + mw + mi * 16 + quad * 4 + r;
            if (row < M) {
                #pragma unroll
                for (int ni = 0; ni < 4; ++ni)
                    C[(size_t)row * HD + nw + ni * 16 + l16] = (__bf16)acc[mi][ni][r];
            }
        }
    }
}

// ---- CSR gather-aggregate: one wave per node, unroll-4/2 edge pipeline ------
__global__ void __launch_bounds__(256) gcn_aggregate(const __bf16* __restrict__ hw,
                                                     const float* __restrict__ selfn,
                                                     const float* __restrict__ bias,
                                                     const unsigned* __restrict__ row_start,
                                                     const int* __restrict__ ecol,
                                                     const float* __restrict__ enorm,
                                                     __bf16* __restrict__ agg) {
    int tid = blockIdx.x * 256 + threadIdx.x;
    int n = tid >> 6;            // one wave (64 lanes) per node
    if (n >= NN) return;
    int c4 = (tid & 63) * 4;
    float s = selfn[n];
    bf16x4 hv = *(const bf16x4*)&hw[(size_t)n * HD + c4];
    float4 acc;
    acc.x = (float)hv[0] * s + bias[c4 + 0];
    acc.y = (float)hv[1] * s + bias[c4 + 1];
    acc.z = (float)hv[2] * s + bias[c4 + 2];
    acc.w = (float)hv[3] * s + bias[c4 + 3];
    unsigned e0 = row_start[n], e1 = row_start[n + 1];
    unsigned e = e0;
    for (; e + 4 <= e1; e += 4) {
        int sv0 = ecol[e], sv1 = ecol[e + 1], sv2 = ecol[e + 2], sv3 = ecol[e + 3];
        float nm0 = enorm[e], nm1 = enorm[e + 1], nm2 = enorm[e + 2], nm3 = enorm[e + 3];
        bf16x4 u0 = *(const bf16x4*)&hw[(size_t)sv0 * HD + c4];
        bf16x4 u1 = *(const bf16x4*)&hw[(size_t)sv1 * HD + c4];
        bf16x4 u2 = *(const bf16x4*)&hw[(size_t)sv2 * HD + c4];
        bf16x4 u3 = *(const bf16x4*)&hw[(size_t)sv3 * HD + c4];
        acc.x += (float)u0[0] * nm0 + (float)u1[0] * nm1 + (float)u2[0] * nm2 + (float)u3[0] * nm3;
        acc.y += (float)u0[1] * nm0 + (float)u1[1] * nm1 + (float)u2[1] * nm2 + (float)u3[1] * nm3;
        acc.z += (float)u0[2] * nm0 + (float)u1[2] * nm1 + (float)u2[2] * nm2 + (float)u3[2] * nm3;
        acc.w += (float)u0[3] * nm0 + (float)u1[3] * nm1 + (float)u2[3] * nm2 + (float)u3[3] * nm3;
    }
    for (; e + 2 <= e1; e += 2) {
        int sv0 = ecol[e], sv1 = ecol[e + 1];
        float nm0 = enorm[e], nm1 = enorm[e + 1];
        bf16x4 u0 = *(const bf16x4*)&hw[(size_t)sv0 * HD + c4];
        bf16x4 u1 = *(const bf16x4*)&hw[(size_t)sv1 * HD + c4];
        acc.x += (float)u0[0] * nm0 + (float)u1[0] * nm1;
        acc.y += (float)u0[1] * nm0 + (float)u1[1] * nm1;
        acc.z += (float)u0[2] * nm0 + (float)u1[2] * nm1;
        acc.w += (float)u0[3] * nm0 + (float)u1[3] * nm1;
    }
    if (e < e1) {
        int sv = ecol[e];
        float nm = enorm[e];
        bf16x4 u = *(const bf16x4*)&hw[(size_t)sv * HD + c4];
        acc.x += (float)u[0] * nm;
        acc.y += (float)u[1] * nm;
        acc.z += (float)u[2] * nm;
        acc.w += (float)u[3] * nm;
    }
    bf16x4 o;
    o[0] = (__bf16)acc.x; o[1] = (__bf16)acc.y;
    o[2] = (__bf16)acc.z; o[3] = (__bf16)acc.w;
    *(bf16x4*)&agg[(size_t)n * HD + c4] = o;
}

// ---- BN stats, two-stage, atomic-free (bf16 input, PB=2048) -----------------
__global__ void __launch_bounds__(256) bn_partial(const __bf16* __restrict__ h,
                                                  float* __restrict__ part) {
    __shared__ float4 ssum[4][64];
    __shared__ float4 sss[4][64];
    int t = threadIdx.x;
    int l = t & 63, w = t >> 6;
    int c4 = l * 4;
    float4 lsum = make_float4(0.f, 0.f, 0.f, 0.f);
    float4 lss  = make_float4(0.f, 0.f, 0.f, 0.f);
    for (int n = blockIdx.x * 4 + w; n < NN; n += PB * 4) {
        bf16x4 b = *(const bf16x4*)&h[(size_t)n * HD + c4];
        float vx = (float)b[0], vy = (float)b[1], vz = (float)b[2], vw = (float)b[3];
        lsum.x += vx; lsum.y += vy; lsum.z += vz; lsum.w += vw;
        lss.x += vx * vx; lss.y += vy * vy; lss.z += vz * vz; lss.w += vw * vw;
    }
    ssum[w][l] = lsum;
    sss[w][l]  = lss;
    __syncthreads();
    if (w == 0) {
        float4 a0 = ssum[0][l], a1 = ssum[1][l], a2 = ssum[2][l], a3 = ssum[3][l];
        float4 q0 = sss[0][l],  q1 = sss[1][l],  q2 = sss[2][l],  q3 = sss[3][l];
        part[(c4 + 0) * PB + blockIdx.x] = a0.x + a1.x + a2.x + a3.x;
        part[(c4 + 1) * PB + blockIdx.x] = a0.y + a1.y + a2.y + a3.y;
        part[(c4 + 2) * PB + blockIdx.x] = a0.z + a1.z + a2.z + a3.z;
        part[(c4 + 3) * PB + blockIdx.x] = a0.w + a1.w + a2.w + a3.w;
        part[(HD + c4 + 0) * PB + blockIdx.x] = q0.x + q1.x + q2.x + q3.x;
        part[(HD + c4 + 1) * PB + blockIdx.x] = q0.y + q1.y + q2.y + q3.y;
        part[(HD + c4 + 2) * PB + blockIdx.x] = q0.z + q1.z + q2.z + q3.z;
        part[(HD + c4 + 3) * PB + blockIdx.x] = q0.w + q1.w + q2.w + q3.w;
    }
}

// Stage 2: one block per column c; reduce partials, emit scale/shift.
__global__ void __launch_bounds__(256) bn_scale(const float* __restrict__ part,
                                                const float* __restrict__ gamma,
                                                const float* __restrict__ beta,
                                                float* __restrict__ scale,
                                                float* __restrict__ shift) {
    __shared__ float rs[256], rq[256];
    int t = threadIdx.x;
    int c = blockIdx.x;
    float s = 0.f, q = 0.f;
    for (int j = t; j < PB; j += 256) {
        s += part[c * PB + j];
        q += part[(HD + c) * PB + j];
    }
    rs[t] = s; rq[t] = q;
    __syncthreads();
    for (int off = 128; off > 0; off >>= 1) {
        if (t < off) { rs[t] += rs[t + off]; rq[t] += rq[t + off]; }
        __syncthreads();
    }
    if (t == 0) {
        const float inv_n = 1.0f / (float)NN;
        float mu  = rs[0] * inv_n;
        float var = rq[0] * inv_n - mu * mu;
        float rstd = rsqrtf(var + 1e-5f);
        float sc = gamma[c] * rstd;
        scale[c] = sc;
        shift[c] = beta[c] - mu * sc;
    }
}

// ---- layer-2 collapse: z[n] = relu_bn(buf0[n]) . w2lw  (one wave per node) --
__global__ void __launch_bounds__(256) bn_dot(const __bf16* __restrict__ h,
                                              const float* __restrict__ scale,
                                              const float* __restrict__ shift,
                                              const float* __restrict__ w2lw,
                                              float* __restrict__ z) {
    int tid = blockIdx.x * 256 + threadIdx.x;
    int n = tid >> 6;
    if (n >= NN) return;
    int l = tid & 63;
    int c4 = l * 4;
    bf16x4 a = *(const bf16x4*)&h[(size_t)n * HD + c4];
    float4 sc = *(const float4*)&scale[c4];
    float4 sh = *(const float4*)&shift[c4];
    float4 wv = *(const float4*)&w2lw[c4];
    float d = fmaxf((float)a[0] * sc.x + sh.x, 0.f) * wv.x
            + fmaxf((float)a[1] * sc.y + sh.y, 0.f) * wv.y
            + fmaxf((float)a[2] * sc.z + sh.z, 0.f) * wv.z
            + fmaxf((float)a[3] * sc.w + sh.w, 0.f) * wv.w;
    #pragma unroll
    for (int off = 32; off > 0; off >>= 1) d += __shfl_down(d, off, 64);
    if (l == 0) z[n] = d;
}

// ---- fused final: per-graph wave; lanes stride nodes; scalar edge loop ------
__global__ void __launch_bounds__(256) pool_fused(const float* __restrict__ z,
                                                  const float* __restrict__ selfn,
                                                  const float* __restrict__ b2lw,
                                                  const unsigned* __restrict__ row_start,
                                                  const int* __restrict__ ecol,
                                                  const float* __restrict__ enorm,
                                                  const unsigned* __restrict__ gstart,
                                                  const float* __restrict__ lb,
                                                  float* __restrict__ out) {
    int tid = blockIdx.x * 256 + threadIdx.x;
    int g = tid >> 6;
    if (g >= NG) return;
    int l = tid & 63;
    unsigned s0 = gstart[g], s1 = gstart[g + 1];
    float bb = *b2lw;
    float s = 0.f;
    for (unsigned i = s0 + l; i < s1; i += 64) {
        float d = selfn[i] * z[i] + bb;
        unsigned e0 = row_start[i], e1 = row_start[i + 1];
        for (unsigned e = e0; e < e1; ++e)
            d += enorm[e] * z[ecol[e]];
        s += d;
    }
    #pragma unroll
    for (int off = 32; off > 0; off >>= 1) s += __shfl_down(s, off, 64);
    if (l == 0) out[g] = s / fmaxf((float)(s1 - s0), 1.0f) + lb[0];
}

// ---- driver -----------------------------------------------------------------
extern "C" void kernel_launch(void* const* d_in, const int* in_sizes, int n_in,
                              void* d_out, int out_size, void* d_ws, size_t ws_size,
                              hipStream_t stream) {
    const int*   x     = (const int*)d_in[0];
    const int*   ei    = (const int*)d_in[1];
    const int*   batch = (const int*)d_in[2];
    const float* emb   = (const float*)d_in[3];
    const float* Ws    = (const float*)d_in[4];
    const float* bs    = (const float*)d_in[5];
    const float* gam   = (const float*)d_in[6];
    const float* bet   = (const float*)d_in[7];
    const float* lw    = (const float*)d_in[8];
    const float* lb    = (const float*)d_in[9];
    float* out = (float*)d_out;

    const int* src = ei;
    const int* dst = ei + NE;

    // workspace carve-up (256-B aligned)
    char* p = (char*)d_ws;
    size_t off = 0;
    auto carve = [&](size_t bytes) { void* r = p + off; off = (off + bytes + 255) & ~(size_t)255; return r; };
    __bf16*   buf0   = (__bf16*)carve((size_t)NN * HD * 2);   // agg (bf16)
    __bf16*   buf1   = (__bf16*)carve((size_t)NN * HD * 2);   // hw  (bf16)
    float*    dW0    = (float*)carve(NF * HD * 4);
    float*    bW0    = (float*)carve(HD * 4);
    __bf16*   dW0t   = (__bf16*)carve(HD * 64 * 2);
    __bf16*   Wt     = (__bf16*)carve((size_t)HD * HD * 2);   // layer-1 only
    float*    w2lw   = (float*)carve(HD * 4);
    float*    b2lw   = (float*)carve(256);
    unsigned* deg    = (unsigned*)carve(NN * 4);
    float*    dinv   = (float*)carve(NN * 4);
    float*    selfn  = (float*)carve(NN * 4);
    unsigned* csum   = (unsigned*)carve(256 * 4);
    unsigned* row_s  = (unsigned*)carve((NN + 1) * 4);
    unsigned* cursor = (unsigned*)carve(NN * 4);
    int*      ecol   = (int*)carve(NE * 4);
    float*    enorm  = (float*)carve(NE * 4);
    float*    part   = (float*)carve((size_t)2 * HD * PB * 4);   // 4 MB
    float*    scale  = (float*)carve(HD * 4);
    float*    shift  = (float*)carve(HD * 4);
    unsigned* gstart = (unsigned*)carve((NG + 1) * 4);
    float*    zbuf   = (float*)carve(NN * 4);
    (void)ws_size; (void)n_in; (void)in_sizes; (void)out_size;

    // params (prep_w2lw merged into prep_params)
    prep_params<<<NF + 2, HD, 0, stream>>>(emb, Ws, bs, lw, dW0, bW0, w2lw, b2lw);
    cvt_w_all<<<dim3(HD, 2), HD, 0, stream>>>(Ws, dW0, Wt, dW0t);

    // degrees, CSR build with inline norm + graph bounds in tail blocks
    hipMemsetAsync(deg, 0, NN * 4, stream);
    deg_kernel<<<(NE + 255) / 256, 256, 0, stream>>>(dst, deg, NE);
    chunk_sum_dinv<<<NCH, SCAN_CH, 0, stream>>>(deg, csum, dinv, selfn);
    chunk_apply<<<NCH, SCAN_CH, 0, stream>>>(deg, csum, row_s, cursor);
    csr_fill_gb<<<EB + (NG + 256) / 256, 256, 0, stream>>>(
        src, dst, dinv, cursor, ecol, enorm, batch, gstart);

    // layer 0: MFMA encoder -> buf1, aggregate -> buf0, BN stats (two-stage)
    encoder_mfma<<<dim3((NN + 127) / 128, 2), 256, 0, stream>>>(x, dW0t, bW0, buf1);
    gcn_aggregate<<<(NN * 64 + 255) / 256, 256, 0, stream>>>(
        buf1, selfn, bs, row_s, ecol, enorm, buf0);
    bn_partial<<<PB, 256, 0, stream>>>(buf0, part);
    bn_scale<<<HD, 256, 0, stream>>>(part, gam, bet, scale, shift);

    // layer 1: MFMA GEMM 128x256 (A read once) -> buf1, aggregate -> buf0, stats
    gemm_mfma<<<(NN + 127) / 128, 512, 0, stream>>>(
        buf0, Wt, buf1, NN, scale, shift);
    gcn_aggregate<<<(NN * 64 + 255) / 256, 256, 0, stream>>>(
        buf1, selfn, bs + HD, row_s, ecol, enorm, buf0);
    bn_partial<<<PB, 256, 0, stream>>>(buf0, part);
    bn_scale<<<HD, 256, 0, stream>>>(part, gam + HD, bet + HD, scale, shift);

    // layer 2 (collapsed): z = relu_bn(buf0)@(W2 lw); fused agg+pool
    bn_dot<<<(NN * 64 + 255) / 256, 256, 0, stream>>>(buf0, scale, shift, w2lw, zbuf);
    pool_fused<<<(NG * 64 + 255) / 256, 256, 0, stream>>>(
        zbuf, selfn, b2lw, row_s, ecol, enorm, gstart, lb, out);
}